// Round 7
// baseline (909.895 us; speedup 1.0000x reference)
//
#include <hip/hip_runtime.h>
#include <stdint.h>

#define FF 128
#define MFMA __builtin_amdgcn_mfma_f32_16x16x32_bf16

typedef __attribute__((ext_vector_type(8))) short bf8_t;     // 8 x bf16 MFMA frag
typedef __attribute__((ext_vector_type(4))) float f4_t;      // MFMA acc
typedef __attribute__((ext_vector_type(8))) uint16_t us8_t;  // 8 x bf16 bits

__device__ __forceinline__ uint16_t f2bf(float f) {
  union { float f; uint32_t u; } v; v.f = f;
  return (uint16_t)((v.u + 0x7fffu + ((v.u >> 16) & 1u)) >> 16);  // RNE
}
__device__ __forceinline__ float bf2f(uint16_t h) {
  union { uint32_t u; float f; } v; v.u = ((uint32_t)h) << 16;
  return v.f;
}

// Stage one 128x128 bf16 weight matrix (32KB) into LDS, chunk-major:
// wlds byte layout: c*2048 + r*16, c = 16B-col-chunk (0..15), r = row (0..127).
#define STAGE_W(Wp, rsb, cb)                                                   \
  do {                                                                         \
    uint4 tmp_[8];                                                             \
    _Pragma("unroll") for (int j_ = 0; j_ < 8; ++j_) {                         \
      int k_ = j_ * 4 + w;                                                     \
      int r_ = ((k_ & 1) << 6) + lane;                                         \
      int c_ = k_ >> 1;                                                        \
      tmp_[j_] = *(const uint4*)((const char*)(Wp) + (size_t)r_ * (rsb) +      \
                                 (cb) + c_ * 16);                              \
    }                                                                          \
    _Pragma("unroll") for (int j_ = 0; j_ < 8; ++j_) {                         \
      int k_ = j_ * 4 + w;                                                     \
      *(uint4*)((char*)wlds + k_ * 1024 + lane * 16) = tmp_[j_];               \
    }                                                                          \
  } while (0)

// ---------------- weights f32 -> bf16 ----------------
// layout: [wsl | w1n | w2n | w1d | w2d] each 128x128, then wgat 128x384
__global__ __launch_bounds__(256) void cvt_w_k(
    const float* __restrict__ wsl, const float* __restrict__ w1n,
    const float* __restrict__ w2n, const float* __restrict__ w1d,
    const float* __restrict__ w2d, const float* __restrict__ wgat,
    uint16_t* __restrict__ o) {
  int i = blockIdx.x * 256 + threadIdx.x;
  const int NW = 5 * 16384;
  if (i >= NW + 49152) return;
  float v;
  if (i < NW) {
    int wsel = i >> 14, j = i & 16383;
    const float* p = (wsel == 0) ? wsl : (wsel == 1) ? w1n : (wsel == 2) ? w2n
                     : (wsel == 3) ? w1d : w2d;
    v = p[j];
  } else {
    v = wgat[i - NW];
  }
  o[i] = f2bf(v);
}

// ---------------- x f32 -> bf16 ----------------
__global__ __launch_bounds__(256) void cvt_x_k(const float* __restrict__ x,
                                               uint16_t* __restrict__ xb, int n4) {
  int i = blockIdx.x * 256 + threadIdx.x;
  if (i >= n4) return;
  float4 v = ((const float4*)x)[i];
  uint2 o;
  o.x = ((uint32_t)f2bf(v.y) << 16) | f2bf(v.x);
  o.y = ((uint32_t)f2bf(v.w) << 16) | f2bf(v.z);
  ((uint2*)xb)[i] = o;
}

// ---------------- counting sort of edges by key = dst*2 + type ----------------
__global__ __launch_bounds__(256) void hist_k(const int* __restrict__ dst,
                                              const int* __restrict__ ety,
                                              int* __restrict__ hist, int E) {
  int i = blockIdx.x * 256 + threadIdx.x;
  if (i < E) atomicAdd(&hist[(dst[i] << 1) | ety[i]], 1);
}

__global__ __launch_bounds__(256) void scan1_k(const int* __restrict__ hist,
                                               int* __restrict__ off,
                                               int* __restrict__ bsum, int nbins) {
  int i = blockIdx.x * 256 + threadIdx.x;
  int v = (i < nbins) ? hist[i] : 0;
  int lane = threadIdx.x & 63, w = threadIdx.x >> 6;
  int s = v;
#pragma unroll
  for (int d = 1; d < 64; d <<= 1) {
    int o = __shfl_up(s, (unsigned)d, 64);
    if (lane >= d) s += o;
  }
  __shared__ int wsum[4];
  if (lane == 63) wsum[w] = s;
  __syncthreads();
  int add = 0;
  for (int k = 0; k < w; ++k) add += wsum[k];
  s += add;
  if (i < nbins) off[i] = s - v;  // exclusive
  if (threadIdx.x == 255) bsum[blockIdx.x] = s;
}

__global__ __launch_bounds__(1024) void scan2_k(int* __restrict__ bsum, int nb) {
  int t = threadIdx.x;
  int v = (t < nb) ? bsum[t] : 0;
  int lane = t & 63, w = t >> 6;
  int s = v;
#pragma unroll
  for (int d = 1; d < 64; d <<= 1) {
    int o = __shfl_up(s, (unsigned)d, 64);
    if (lane >= d) s += o;
  }
  __shared__ int ws[16];
  if (lane == 63) ws[w] = s;
  __syncthreads();
  int add = 0;
  for (int k = 0; k < w; ++k) add += ws[k];
  s += add;
  if (t < nb) bsum[t] = s - v;
}

// finalize fine offsets; also init coarse-bucket cursors ccur[b] = off[b*512]
__global__ __launch_bounds__(256) void scan3_k(int* __restrict__ off,
                                               int* __restrict__ ccur,
                                               const int* __restrict__ bsum,
                                               int nbins, int E) {
  int i = blockIdx.x * 256 + threadIdx.x;
  if (i < nbins) {
    int v = off[i] + bsum[blockIdx.x];
    off[i] = v;
    if ((i & 511) == 0) ccur[i >> 9] = v;
  }
  if (i == nbins) off[i] = E;
}

// ---------------- pass 1: coarse bucket scatter (391 hot frontiers) ----------------
__global__ __launch_bounds__(256) void bucketize_k(const int* __restrict__ src,
                                                   const int* __restrict__ dst,
                                                   const int* __restrict__ ety,
                                                   int* __restrict__ ccur,
                                                   uint32_t* __restrict__ bk, int E) {
  int i = blockIdx.x * 256 + threadIdx.x;
  if (i < E) {
    int bin = (dst[i] << 1) | ety[i];
    int pos = atomicAdd(&ccur[bin >> 9], 1);
    bk[pos] = (uint32_t)src[i] | ((uint32_t)(bin & 511) << 17);
  }
}

// ---------------- pass 2: fine scatter within bucket (LDS cursors, 16KB window) ----------------
__global__ __launch_bounds__(256) void sctfine_k(const int* __restrict__ off,
                                                 const uint32_t* __restrict__ bk,
                                                 int* __restrict__ ssrc, int nbins) {
  __shared__ int lcur[512];
  const int b = blockIdx.x;
  const int binbase = b << 9;
  const int binend = min(binbase + 512, nbins);
  for (int j = threadIdx.x; j < binend - binbase; j += 256)
    lcur[j] = off[binbase + j];
  __syncthreads();
  const int estart = off[binbase], eend = off[binend];
  for (int i = estart + (int)threadIdx.x; i < eend; i += 256) {
    uint32_t pk = bk[i];
    int pos = atomicAdd(&lcur[pk >> 17], 1);
    ssrc[pos] = (int)(pk & 0x1FFFFu);
  }
}

// ---------------- segment-sum (bf16 gather) + own row: emits bf16 (x+agg) ----------------
__global__ __launch_bounds__(256) void agg_k(const int* __restrict__ off,
                                             const int* __restrict__ ssrc,
                                             const uint16_t* __restrict__ xb,
                                             const float* __restrict__ x,
                                             uint16_t* __restrict__ xanb,
                                             uint16_t* __restrict__ xadb, int nbins) {
  int wid = (blockIdx.x * 256 + threadIdx.x) >> 6;
  int lane = threadIdx.x & 63;
  if (wid >= nbins) return;
  int e = off[wid], end = off[wid + 1];
  float ax = 0.f, ay = 0.f, bx = 0.f, by = 0.f;
  for (; e + 7 < end; e += 8) {
    uint32_t v0 = ((const uint32_t*)(xb + (size_t)ssrc[e] * FF))[lane];
    uint32_t v1 = ((const uint32_t*)(xb + (size_t)ssrc[e + 1] * FF))[lane];
    uint32_t v2 = ((const uint32_t*)(xb + (size_t)ssrc[e + 2] * FF))[lane];
    uint32_t v3 = ((const uint32_t*)(xb + (size_t)ssrc[e + 3] * FF))[lane];
    uint32_t v4 = ((const uint32_t*)(xb + (size_t)ssrc[e + 4] * FF))[lane];
    uint32_t v5 = ((const uint32_t*)(xb + (size_t)ssrc[e + 5] * FF))[lane];
    uint32_t v6 = ((const uint32_t*)(xb + (size_t)ssrc[e + 6] * FF))[lane];
    uint32_t v7 = ((const uint32_t*)(xb + (size_t)ssrc[e + 7] * FF))[lane];
    ax += bf2f((uint16_t)(v0 & 0xffffu)) + bf2f((uint16_t)(v2 & 0xffffu)) +
          bf2f((uint16_t)(v4 & 0xffffu)) + bf2f((uint16_t)(v6 & 0xffffu));
    ay += bf2f((uint16_t)(v0 >> 16)) + bf2f((uint16_t)(v2 >> 16)) +
          bf2f((uint16_t)(v4 >> 16)) + bf2f((uint16_t)(v6 >> 16));
    bx += bf2f((uint16_t)(v1 & 0xffffu)) + bf2f((uint16_t)(v3 & 0xffffu)) +
          bf2f((uint16_t)(v5 & 0xffffu)) + bf2f((uint16_t)(v7 & 0xffffu));
    by += bf2f((uint16_t)(v1 >> 16)) + bf2f((uint16_t)(v3 >> 16)) +
          bf2f((uint16_t)(v5 >> 16)) + bf2f((uint16_t)(v7 >> 16));
  }
  for (; e + 1 < end; e += 2) {
    uint32_t v0 = ((const uint32_t*)(xb + (size_t)ssrc[e] * FF))[lane];
    uint32_t v1 = ((const uint32_t*)(xb + (size_t)ssrc[e + 1] * FF))[lane];
    ax += bf2f((uint16_t)(v0 & 0xffffu));
    ay += bf2f((uint16_t)(v0 >> 16));
    bx += bf2f((uint16_t)(v1 & 0xffffu));
    by += bf2f((uint16_t)(v1 >> 16));
  }
  if (e < end) {
    uint32_t v0 = ((const uint32_t*)(xb + (size_t)ssrc[e] * FF))[lane];
    ax += bf2f((uint16_t)(v0 & 0xffffu));
    ay += bf2f((uint16_t)(v0 >> 16));
  }
  ax += bx;
  ay += by;
  int n = wid >> 1;
  float2 xo = ((const float2*)(x + (size_t)n * FF))[lane];
  ax += xo.x;
  ay += xo.y;
  uint32_t o = ((uint32_t)f2bf(ay) << 16) | f2bf(ax);
  uint16_t* dstp = (wid & 1) ? xadb : xanb;
  ((uint32_t*)(dstp + (size_t)n * FF))[lane] = o;
}

// ---------------- stage 1: branch GEMM1s, weights staged in LDS + BN stats ----------------
__global__ __launch_bounds__(256) void gemm1_k(
    const uint16_t* __restrict__ xanb, const uint16_t* __restrict__ xadb,
    const uint16_t* __restrict__ wbf, const float* __restrict__ b1n,
    const float* __restrict__ b1d, uint16_t* __restrict__ h1n,
    uint16_t* __restrict__ h1d, float* __restrict__ gstats, int N) {
  __shared__ __align__(16) uint16_t wlds[16384];
  __shared__ float sstat[4][4][128];
  const int tid = threadIdx.x;
  const int lane = tid & 63, w = tid >> 6;
  const int lr = lane & 15, lg = lane >> 4;
  const int rowbase = blockIdx.x * 128 + w * 32;
  const int arow0 = min(rowbase + lr, N - 1);
  const int arow1 = min(rowbase + 16 + lr, N - 1);

  f4_t acc[2][8];
  const f4_t zz = {0.f, 0.f, 0.f, 0.f};
  bf8_t a0[4], a1[4];

  STAGE_W(wbf + 16384, 256, 0);
#pragma unroll
  for (int s = 0; s < 4; ++s) {
    const int k0 = s * 32 + lg * 8;
    a0[s] = *(const bf8_t*)(xanb + (size_t)arow0 * FF + k0);
    a1[s] = *(const bf8_t*)(xanb + (size_t)arow1 * FF + k0);
  }
  __syncthreads();

#pragma unroll 1
  for (int gi = 0; gi < 2; ++gi) {
#pragma unroll
    for (int rg = 0; rg < 2; ++rg)
#pragma unroll
      for (int t = 0; t < 8; ++t) acc[rg][t] = zz;
#pragma unroll
    for (int s = 0; s < 4; ++s) {
#pragma unroll
      for (int t = 0; t < 8; ++t) {
        bf8_t b = *(const bf8_t*)&wlds[(s * 4 + lg) * 1024 + (t * 16 + lr) * 8];
        acc[0][t] = MFMA(a0[s], b, acc[0][t], 0, 0, 0);
        acc[1][t] = MFMA(a1[s], b, acc[1][t], 0, 0, 0);
      }
    }
    const float* bp = gi ? b1d : b1n;
    uint16_t* hp = gi ? h1d : h1n;
#pragma unroll
    for (int t = 0; t < 8; ++t) {
      const int col = t * 16 + lr;
      const float b = bp[col];
      float sum = 0.f, ss = 0.f;
#pragma unroll
      for (int rg = 0; rg < 2; ++rg)
#pragma unroll
        for (int r = 0; r < 4; ++r) {
          const int row = rowbase + rg * 16 + lg * 4 + r;
          const float h = acc[rg][t][r] + b;
          if (row < N) {
            hp[(size_t)row * FF + col] = f2bf(h);
            sum += h;
            ss += h * h;
          }
        }
      sum += __shfl_xor(sum, 16, 64);
      sum += __shfl_xor(sum, 32, 64);
      ss += __shfl_xor(ss, 16, 64);
      ss += __shfl_xor(ss, 32, 64);
      if (lane < 16) {
        sstat[w][gi * 2 + 0][col] = sum;
        sstat[w][gi * 2 + 1][col] = ss;
      }
    }
    if (gi == 0) {
      __syncthreads();
      STAGE_W(wbf + 3 * 16384, 256, 0);
#pragma unroll
      for (int s = 0; s < 4; ++s) {
        const int k0 = s * 32 + lg * 8;
        a0[s] = *(const bf8_t*)(xadb + (size_t)arow0 * FF + k0);
        a1[s] = *(const bf8_t*)(xadb + (size_t)arow1 * FF + k0);
      }
      __syncthreads();
    }
  }
  __syncthreads();
  for (int i = tid; i < 512; i += 256) {
    int a = i >> 7, c = i & 127;
    float v = sstat[0][a][c] + sstat[1][a][c] + sstat[2][a][c] + sstat[3][a][c];
    unsafeAtomicAdd(&gstats[i], v);
  }
}

// ---------------- BN finalize ----------------
__global__ void bnfin_k(const float* __restrict__ gstats,
                        const float* __restrict__ gamn, const float* __restrict__ betn,
                        const float* __restrict__ gamd, const float* __restrict__ betd,
                        float* __restrict__ bnp, int N) {
  int i = threadIdx.x;  // 128
  float invN = 1.f / (float)N;
  {
    float mu = gstats[i] * invN;
    float var = gstats[128 + i] * invN - mu * mu;
    float sc = gamn[i] * rsqrtf(var + 1e-5f);
    bnp[i] = sc;
    bnp[128 + i] = betn[i] - mu * sc;
  }
  {
    float mu = gstats[256 + i] * invN;
    float var = gstats[384 + i] * invN - mu * mu;
    float sc = gamd[i] * rsqrtf(var + 1e-5f);
    bnp[256 + i] = sc;
    bnp[384 + i] = betd[i] - mu * sc;
  }
}

// ---------------- stage 2: 6 staged weight phases, B from LDS ----------------
__global__ __launch_bounds__(256) void fuse2_k(
    const uint16_t* __restrict__ xb, const uint16_t* __restrict__ h1n,
    const uint16_t* __restrict__ h1d, const uint16_t* __restrict__ wbf,
    const float* __restrict__ bnp, const float* __restrict__ b_sl,
    const float* __restrict__ b2n, const float* __restrict__ b2d,
    const float* __restrict__ bgat, float* __restrict__ out, int N) {
  __shared__ __align__(16) uint16_t wlds[16384];      // staged weight (32KB)
  __shared__ __align__(16) uint16_t smt[4][16][136];  // per-wave tile, reused 3x
  const int tid = threadIdx.x;
  const int lane = tid & 63, w = tid >> 6;
  const int lr = lane & 15, lg = lane >> 4;
  const int rowbase = blockIdx.x * 64 + w * 16;
  const int arow = min(rowbase + lr, N - 1);
  const uint16_t* wg = wbf + 5 * 16384;

  f4_t sum[8];
  f4_t accG[8];
  f4_t wk[8];
  const f4_t zz = {0.f, 0.f, 0.f, 0.f};

#define GATE_PHASE()                                                             \
  do {                                                                          \
    _Pragma("unroll") for (int s = 0; s < 4; ++s) {                             \
      bf8_t a = *(const bf8_t*)&smt[w][lr][s * 32 + lg * 8];                    \
      _Pragma("unroll") for (int t = 0; t < 8; ++t) {                           \
        bf8_t b = *(const bf8_t*)&wlds[(s * 4 + lg) * 1024 + (t * 16 + lr) * 8]; \
        accG[t] = MFMA(a, b, accG[t], 0, 0, 0);                                 \
      }                                                                         \
    }                                                                           \
  } while (0)

#define BRANCH_PHASE(hv, bnb, bp, ADDSUM)                                        \
  do {                                                                          \
    _Pragma("unroll") for (int t = 0; t < 8; ++t) wk[t] = zz;                   \
    _Pragma("unroll") for (int s = 0; s < 4; ++s) {                             \
      const int k0 = s * 32 + lg * 8;                                           \
      f4_t sc0 = *(const f4_t*)((bnb) + k0);                                    \
      f4_t sc1 = *(const f4_t*)((bnb) + k0 + 4);                                \
      f4_t sh0 = *(const f4_t*)((bnb) + 128 + k0);                              \
      f4_t sh1 = *(const f4_t*)((bnb) + 128 + k0 + 4);                          \
      bf8_t a;                                                                  \
      _Pragma("unroll") for (int j = 0; j < 4; ++j) {                           \
        a[j] = (short)f2bf(fmaxf(bf2f((hv)[s][j]) * sc0[j] + sh0[j], 0.f));     \
        a[j + 4] =                                                              \
            (short)f2bf(fmaxf(bf2f((hv)[s][j + 4]) * sc1[j] + sh1[j], 0.f));    \
      }                                                                         \
      _Pragma("unroll") for (int t = 0; t < 8; ++t) {                           \
        bf8_t b = *(const bf8_t*)&wlds[(s * 4 + lg) * 1024 + (t * 16 + lr) * 8]; \
        wk[t] = MFMA(a, b, wk[t], 0, 0, 0);                                     \
      }                                                                         \
    }                                                                           \
    _Pragma("unroll") for (int t = 0; t < 8; ++t) {                             \
      const int col = t * 16 + lr;                                              \
      const float bb = (bp)[col];                                               \
      _Pragma("unroll") for (int r = 0; r < 4; ++r) {                           \
        const float v = wk[t][r] + bb;                                          \
        if (ADDSUM) sum[t][r] += v;                                             \
        smt[w][lg * 4 + r][col] = f2bf(v);                                      \
      }                                                                         \
    }                                                                           \
  } while (0)

  bf8_t xa[4];
#pragma unroll
  for (int s = 0; s < 4; ++s)
    xa[s] = *(const bf8_t*)(xb + (size_t)arow * FF + s * 32 + lg * 8);

  STAGE_W(wbf, 256, 0);  // wsl
  __syncthreads();

#pragma unroll
  for (int t = 0; t < 8; ++t) sum[t] = zz;
#pragma unroll
  for (int s = 0; s < 4; ++s) {
#pragma unroll
    for (int t = 0; t < 8; ++t) {
      bf8_t b = *(const bf8_t*)&wlds[(s * 4 + lg) * 1024 + (t * 16 + lr) * 8];
      sum[t] = MFMA(xa[s], b, sum[t], 0, 0, 0);
    }
  }
#pragma unroll
  for (int t = 0; t < 8; ++t) {
    const int col = t * 16 + lr;
    const float b = b_sl[col];
#pragma unroll
    for (int r = 0; r < 4; ++r) {
      sum[t][r] += b;
      smt[w][lg * 4 + r][col] = f2bf(sum[t][r]);
    }
  }
  us8_t hvn[4];
#pragma unroll
  for (int s = 0; s < 4; ++s)
    hvn[s] = *(const us8_t*)(h1n + (size_t)arow * FF + s * 32 + lg * 8);

  __syncthreads();
  STAGE_W(wg, 768, 0);  // wgat block 0
  __syncthreads();
#pragma unroll
  for (int t = 0; t < 8; ++t) accG[t] = zz;
  GATE_PHASE();

  __syncthreads();
  STAGE_W(wbf + 2 * 16384, 256, 0);  // w2n
  __syncthreads();
  BRANCH_PHASE(hvn, bnp, b2n, 1);
  us8_t hvd[4];
#pragma unroll
  for (int s = 0; s < 4; ++s)
    hvd[s] = *(const us8_t*)(h1d + (size_t)arow * FF + s * 32 + lg * 8);

  __syncthreads();
  STAGE_W(wg, 768, 256);  // wgat block 1
  __syncthreads();
  GATE_PHASE();

  __syncthreads();
  STAGE_W(wbf + 4 * 16384, 256, 0);  // w2d
  __syncthreads();
  BRANCH_PHASE(hvd, bnp + 256, b2d, 0);

  __syncthreads();
  STAGE_W(wg, 768, 512);  // wgat block 2
  __syncthreads();
  GATE_PHASE();

  float bg[8];
#pragma unroll
  for (int t = 0; t < 8; ++t) bg[t] = bgat[t * 16 + lr];
#pragma unroll
  for (int r = 0; r < 4; ++r) {
    float lv[8];
#pragma unroll
    for (int t = 0; t < 8; ++t) lv[t] = accG[t][r] + bg[t];
    float m = lv[0];
#pragma unroll
    for (int t = 1; t < 8; ++t) m = fmaxf(m, lv[t]);
#pragma unroll
    for (int d = 1; d < 16; d <<= 1) m = fmaxf(m, __shfl_xor(m, d, 16));
    float g[8];
    float run = 0.f;
#pragma unroll
    for (int t = 0; t < 8; ++t) {
      float p = __expf(lv[t] - m);
      float scn = p;
#pragma unroll
      for (int d = 1; d < 16; d <<= 1) {
        float o = __shfl_up(scn, (unsigned)d, 16);
        if (lr >= d) scn += o;
      }
      g[t] = run + scn;
      run += __shfl(scn, 15, 16);
    }
    const float inv = 1.f / run;
    const int row = rowbase + lg * 4 + r;
    if (row < N) {
      const int lrow = lg * 4 + r;
#pragma unroll
      for (int t = 0; t < 8; ++t) {
        const int col = t * 16 + lr;
        const float xdf = bf2f(smt[w][lrow][127 - col]);
        out[(size_t)row * FF + col] = sum[t][r] + xdf * (g[t] * inv);
      }
    }
  }
#undef GATE_PHASE
#undef BRANCH_PHASE
}

extern "C" void kernel_launch(void* const* d_in, const int* in_sizes, int n_in,
                              void* d_out, int out_size, void* d_ws, size_t ws_size,
                              hipStream_t stream) {
  const float* x = (const float*)d_in[0];
  const int* eidx = (const int*)d_in[1];
  const int* etype = (const int*)d_in[2];
  const float* w_sl = (const float*)d_in[3];
  const float* b_sl = (const float*)d_in[4];
  const float* w1n = (const float*)d_in[5];
  const float* b1n = (const float*)d_in[6];
  const float* gamn = (const float*)d_in[7];
  const float* betn = (const float*)d_in[8];
  const float* w2n = (const float*)d_in[9];
  const float* b2n = (const float*)d_in[10];
  const float* w1d = (const float*)d_in[11];
  const float* b1d = (const float*)d_in[12];
  const float* gamd = (const float*)d_in[13];
  const float* betd = (const float*)d_in[14];
  const float* w2d = (const float*)d_in[15];
  const float* b2d = (const float*)d_in[16];
  const float* wgat = (const float*)d_in[17];
  const float* bgat = (const float*)d_in[18];
  float* out = (float*)d_out;

  const int N = in_sizes[0] / FF;
  const int E = in_sizes[2];
  const int* src = eidx;
  const int* dst = eidx + E;
  const int nbins = 2 * N;
  const int nbuckets = (nbins + 511) >> 9;

  const size_t NF = (size_t)N * FF;
  float* gstats = (float*)d_ws;
  float* bnp = gstats + 512;
  uint16_t* wbf = (uint16_t*)(bnp + 512);  // 131072 u16
  uint16_t* xb = wbf + 131072;             // NF
  uint16_t* xanb = xb + NF;
  uint16_t* xadb = xanb + NF;
  uint16_t* h1n = xadb + NF;
  uint16_t* h1d = h1n + NF;
  int* hist = (int*)(h1d + NF);
  int* off = hist + nbins;        // nbins+1
  int* ccur = off + nbins + 1;    // nbuckets
  int* bsum = ccur + nbuckets;    // <=1024
  int* ssrc = bsum + 1024;        // E
  uint32_t* bk = (uint32_t*)(ssrc + E);  // E

  const int nb1 = (nbins + 255) / 256;

  hipMemsetAsync(hist, 0, (size_t)nbins * sizeof(int), stream);
  hipMemsetAsync(gstats, 0, 512 * sizeof(float), stream);
  cvt_w_k<<<512, 256, 0, stream>>>(w_sl, w1n, w2n, w1d, w2d, wgat, wbf);
  cvt_x_k<<<(int)((NF / 4 + 255) / 256), 256, 0, stream>>>(x, xb, (int)(NF / 4));

  hist_k<<<(E + 255) / 256, 256, 0, stream>>>(dst, etype, hist, E);
  scan1_k<<<nb1, 256, 0, stream>>>(hist, off, bsum, nbins);
  scan2_k<<<1, 1024, 0, stream>>>(bsum, nb1);
  scan3_k<<<(nbins + 256) / 256, 256, 0, stream>>>(off, ccur, bsum, nbins, E);
  bucketize_k<<<(E + 255) / 256, 256, 0, stream>>>(src, dst, etype, ccur, bk, E);
  sctfine_k<<<nbuckets, 256, 0, stream>>>(off, bk, ssrc, nbins);
  agg_k<<<(nbins + 3) / 4, 256, 0, stream>>>(off, ssrc, xb, x, xanb, xadb, nbins);

  gemm1_k<<<(N + 127) / 128, 256, 0, stream>>>(xanb, xadb, wbf, b1n, b1d, h1n, h1d,
                                               gstats, N);
  bnfin_k<<<1, 128, 0, stream>>>(gstats, gamn, betn, gamd, betd, bnp, N);
  fuse2_k<<<(N + 63) / 64, 256, 0, stream>>>(xb, h1n, h1d, wbf, bnp, b_sl, b2n, b2d,
                                             bgat, out, N);
}

// Round 8
// 377.348 us; speedup vs baseline: 2.4113x; 2.4113x over previous
//
#include <hip/hip_runtime.h>
#include <stdint.h>

#define FF 128
#define MFMA __builtin_amdgcn_mfma_f32_16x16x32_bf16

typedef __attribute__((ext_vector_type(8))) short bf8_t;     // 8 x bf16 MFMA frag
typedef __attribute__((ext_vector_type(4))) float f4_t;      // MFMA acc
typedef __attribute__((ext_vector_type(8))) uint16_t us8_t;  // 8 x bf16 bits

__device__ __forceinline__ uint16_t f2bf(float f) {
  union { float f; uint32_t u; } v; v.f = f;
  return (uint16_t)((v.u + 0x7fffu + ((v.u >> 16) & 1u)) >> 16);  // RNE
}
__device__ __forceinline__ float bf2f(uint16_t h) {
  union { uint32_t u; float f; } v; v.u = ((uint32_t)h) << 16;
  return v.f;
}

// Stage one 128x128 bf16 weight matrix (32KB) into LDS, chunk-major:
// wlds byte layout: c*2048 + r*16, c = 16B-col-chunk (0..15), r = row (0..127).
#define STAGE_W(Wp, rsb, cb)                                                   \
  do {                                                                         \
    uint4 tmp_[8];                                                             \
    _Pragma("unroll") for (int j_ = 0; j_ < 8; ++j_) {                         \
      int k_ = j_ * 4 + w;                                                     \
      int r_ = ((k_ & 1) << 6) + lane;                                         \
      int c_ = k_ >> 1;                                                        \
      tmp_[j_] = *(const uint4*)((const char*)(Wp) + (size_t)r_ * (rsb) +      \
                                 (cb) + c_ * 16);                              \
    }                                                                          \
    _Pragma("unroll") for (int j_ = 0; j_ < 8; ++j_) {                         \
      int k_ = j_ * 4 + w;                                                     \
      *(uint4*)((char*)wlds + k_ * 1024 + lane * 16) = tmp_[j_];               \
    }                                                                          \
  } while (0)

// ---------------- weights f32 -> bf16 ----------------
// layout: [wsl | w1n | w2n | w1d | w2d] each 128x128, then wgat 128x384
__global__ __launch_bounds__(256) void cvt_w_k(
    const float* __restrict__ wsl, const float* __restrict__ w1n,
    const float* __restrict__ w2n, const float* __restrict__ w1d,
    const float* __restrict__ w2d, const float* __restrict__ wgat,
    uint16_t* __restrict__ o) {
  int i = blockIdx.x * 256 + threadIdx.x;
  const int NW = 5 * 16384;
  if (i >= NW + 49152) return;
  float v;
  if (i < NW) {
    int wsel = i >> 14, j = i & 16383;
    const float* p = (wsel == 0) ? wsl : (wsel == 1) ? w1n : (wsel == 2) ? w2n
                     : (wsel == 3) ? w1d : w2d;
    v = p[j];
  } else {
    v = wgat[i - NW];
  }
  o[i] = f2bf(v);
}

// ---------------- x f32 -> bf16 ----------------
__global__ __launch_bounds__(256) void cvt_x_k(const float* __restrict__ x,
                                               uint16_t* __restrict__ xb, int n4) {
  int i = blockIdx.x * 256 + threadIdx.x;
  if (i >= n4) return;
  float4 v = ((const float4*)x)[i];
  uint2 o;
  o.x = ((uint32_t)f2bf(v.y) << 16) | f2bf(v.x);
  o.y = ((uint32_t)f2bf(v.w) << 16) | f2bf(v.z);
  ((uint2*)xb)[i] = o;
}

// ---------------- counting sort of edges by key = dst*2 + type ----------------
__global__ __launch_bounds__(256) void hist_k(const int* __restrict__ dst,
                                              const int* __restrict__ ety,
                                              int* __restrict__ hist, int E) {
  int i = blockIdx.x * 256 + threadIdx.x;
  if (i < E) atomicAdd(&hist[(dst[i] << 1) | ety[i]], 1);
}

__global__ __launch_bounds__(256) void scan1_k(const int* __restrict__ hist,
                                               int* __restrict__ off,
                                               int* __restrict__ bsum, int nbins) {
  int i = blockIdx.x * 256 + threadIdx.x;
  int v = (i < nbins) ? hist[i] : 0;
  int lane = threadIdx.x & 63, w = threadIdx.x >> 6;
  int s = v;
#pragma unroll
  for (int d = 1; d < 64; d <<= 1) {
    int o = __shfl_up(s, (unsigned)d, 64);
    if (lane >= d) s += o;
  }
  __shared__ int wsum[4];
  if (lane == 63) wsum[w] = s;
  __syncthreads();
  int add = 0;
  for (int k = 0; k < w; ++k) add += wsum[k];
  s += add;
  if (i < nbins) off[i] = s - v;  // exclusive
  if (threadIdx.x == 255) bsum[blockIdx.x] = s;
}

__global__ __launch_bounds__(1024) void scan2_k(int* __restrict__ bsum, int nb) {
  int t = threadIdx.x;
  int v = (t < nb) ? bsum[t] : 0;
  int lane = t & 63, w = t >> 6;
  int s = v;
#pragma unroll
  for (int d = 1; d < 64; d <<= 1) {
    int o = __shfl_up(s, (unsigned)d, 64);
    if (lane >= d) s += o;
  }
  __shared__ int ws[16];
  if (lane == 63) ws[w] = s;
  __syncthreads();
  int add = 0;
  for (int k = 0; k < w; ++k) add += ws[k];
  s += add;
  if (t < nb) bsum[t] = s - v;
}

// finalize fine offsets; also init coarse-bucket cursors ccur[b] = off[b*512]
__global__ __launch_bounds__(256) void scan3_k(int* __restrict__ off,
                                               int* __restrict__ ccur,
                                               const int* __restrict__ bsum,
                                               int nbins, int E) {
  int i = blockIdx.x * 256 + threadIdx.x;
  if (i < nbins) {
    int v = off[i] + bsum[blockIdx.x];
    off[i] = v;
    if ((i & 511) == 0) ccur[i >> 9] = v;
  }
  if (i == nbins) off[i] = E;
}

// ---------------- pass 1: LDS-aggregated coarse bucket scatter ----------------
// Block = 256 thr x 16 edges = 4096 edges. Phase A: LDS hist + per-edge rank.
// Phase B: one global atomicAdd per (block,bucket). Phase C: bk[base+rank]=pk.
#define BK_EPT 16
__global__ __launch_bounds__(256) void bucketize_k(const int* __restrict__ src,
                                                   const int* __restrict__ dst,
                                                   const int* __restrict__ ety,
                                                   int* __restrict__ ccur,
                                                   uint32_t* __restrict__ bk,
                                                   int E, int nbuckets) {
  __shared__ int lhist[512];
  __shared__ int lbase[512];
  const int tid = threadIdx.x;
  const int base = blockIdx.x * (256 * BK_EPT);
  for (int j = tid; j < nbuckets; j += 256) lhist[j] = 0;
  __syncthreads();

  uint32_t pk[BK_EPT];  // src | localbin<<17
  uint32_t rk[BK_EPT];  // bucket | rank<<9
#pragma unroll
  for (int j = 0; j < BK_EPT; ++j) {
    int i = base + j * 256 + tid;
    if (i < E) {
      int bin = (dst[i] << 1) | ety[i];
      int bucket = bin >> 9;
      int rank = atomicAdd(&lhist[bucket], 1);
      pk[j] = (uint32_t)src[i] | ((uint32_t)(bin & 511) << 17);
      rk[j] = (uint32_t)bucket | ((uint32_t)rank << 9);
    } else {
      rk[j] = 0xFFFFFFFFu;
    }
  }
  __syncthreads();
  for (int j = tid; j < nbuckets; j += 256) {
    int c = lhist[j];
    lbase[j] = c ? atomicAdd(&ccur[j], c) : 0;
  }
  __syncthreads();
#pragma unroll
  for (int j = 0; j < BK_EPT; ++j) {
    if (rk[j] != 0xFFFFFFFFu) {
      int bucket = (int)(rk[j] & 511u);
      int rank = (int)(rk[j] >> 9);
      bk[lbase[bucket] + rank] = pk[j];
    }
  }
}

// ---------------- pass 2: fine scatter within bucket (LDS cursors, 16KB window) ----------------
__global__ __launch_bounds__(256) void sctfine_k(const int* __restrict__ off,
                                                 const uint32_t* __restrict__ bk,
                                                 int* __restrict__ ssrc, int nbins) {
  __shared__ int lcur[512];
  const int b = blockIdx.x;
  const int binbase = b << 9;
  const int binend = min(binbase + 512, nbins);
  for (int j = threadIdx.x; j < binend - binbase; j += 256)
    lcur[j] = off[binbase + j];
  __syncthreads();
  const int estart = off[binbase], eend = off[binend];
  for (int i = estart + (int)threadIdx.x; i < eend; i += 256) {
    uint32_t pk = bk[i];
    int pos = atomicAdd(&lcur[pk >> 17], 1);
    ssrc[pos] = (int)(pk & 0x1FFFFu);
  }
}

// ---------------- segment-sum (bf16 gather) + own row: emits bf16 (x+agg) ----------------
__global__ __launch_bounds__(256) void agg_k(const int* __restrict__ off,
                                             const int* __restrict__ ssrc,
                                             const uint16_t* __restrict__ xb,
                                             const float* __restrict__ x,
                                             uint16_t* __restrict__ xanb,
                                             uint16_t* __restrict__ xadb, int nbins) {
  int wid = (blockIdx.x * 256 + threadIdx.x) >> 6;
  int lane = threadIdx.x & 63;
  if (wid >= nbins) return;
  int e = off[wid], end = off[wid + 1];
  float ax = 0.f, ay = 0.f, bx = 0.f, by = 0.f;
  for (; e + 7 < end; e += 8) {
    uint32_t v0 = ((const uint32_t*)(xb + (size_t)ssrc[e] * FF))[lane];
    uint32_t v1 = ((const uint32_t*)(xb + (size_t)ssrc[e + 1] * FF))[lane];
    uint32_t v2 = ((const uint32_t*)(xb + (size_t)ssrc[e + 2] * FF))[lane];
    uint32_t v3 = ((const uint32_t*)(xb + (size_t)ssrc[e + 3] * FF))[lane];
    uint32_t v4 = ((const uint32_t*)(xb + (size_t)ssrc[e + 4] * FF))[lane];
    uint32_t v5 = ((const uint32_t*)(xb + (size_t)ssrc[e + 5] * FF))[lane];
    uint32_t v6 = ((const uint32_t*)(xb + (size_t)ssrc[e + 6] * FF))[lane];
    uint32_t v7 = ((const uint32_t*)(xb + (size_t)ssrc[e + 7] * FF))[lane];
    ax += bf2f((uint16_t)(v0 & 0xffffu)) + bf2f((uint16_t)(v2 & 0xffffu)) +
          bf2f((uint16_t)(v4 & 0xffffu)) + bf2f((uint16_t)(v6 & 0xffffu));
    ay += bf2f((uint16_t)(v0 >> 16)) + bf2f((uint16_t)(v2 >> 16)) +
          bf2f((uint16_t)(v4 >> 16)) + bf2f((uint16_t)(v6 >> 16));
    bx += bf2f((uint16_t)(v1 & 0xffffu)) + bf2f((uint16_t)(v3 & 0xffffu)) +
          bf2f((uint16_t)(v5 & 0xffffu)) + bf2f((uint16_t)(v7 & 0xffffu));
    by += bf2f((uint16_t)(v1 >> 16)) + bf2f((uint16_t)(v3 >> 16)) +
          bf2f((uint16_t)(v5 >> 16)) + bf2f((uint16_t)(v7 >> 16));
  }
  for (; e + 1 < end; e += 2) {
    uint32_t v0 = ((const uint32_t*)(xb + (size_t)ssrc[e] * FF))[lane];
    uint32_t v1 = ((const uint32_t*)(xb + (size_t)ssrc[e + 1] * FF))[lane];
    ax += bf2f((uint16_t)(v0 & 0xffffu));
    ay += bf2f((uint16_t)(v0 >> 16));
    bx += bf2f((uint16_t)(v1 & 0xffffu));
    by += bf2f((uint16_t)(v1 >> 16));
  }
  if (e < end) {
    uint32_t v0 = ((const uint32_t*)(xb + (size_t)ssrc[e] * FF))[lane];
    ax += bf2f((uint16_t)(v0 & 0xffffu));
    ay += bf2f((uint16_t)(v0 >> 16));
  }
  ax += bx;
  ay += by;
  int n = wid >> 1;
  float2 xo = ((const float2*)(x + (size_t)n * FF))[lane];
  ax += xo.x;
  ay += xo.y;
  uint32_t o = ((uint32_t)f2bf(ay) << 16) | f2bf(ax);
  uint16_t* dstp = (wid & 1) ? xadb : xanb;
  ((uint32_t*)(dstp + (size_t)n * FF))[lane] = o;
}

// ---------------- stage 1: branch GEMM1s, weights staged in LDS + BN stats ----------------
__global__ __launch_bounds__(256) void gemm1_k(
    const uint16_t* __restrict__ xanb, const uint16_t* __restrict__ xadb,
    const uint16_t* __restrict__ wbf, const float* __restrict__ b1n,
    const float* __restrict__ b1d, uint16_t* __restrict__ h1n,
    uint16_t* __restrict__ h1d, float* __restrict__ gstats, int N) {
  __shared__ __align__(16) uint16_t wlds[16384];
  __shared__ float sstat[4][4][128];
  const int tid = threadIdx.x;
  const int lane = tid & 63, w = tid >> 6;
  const int lr = lane & 15, lg = lane >> 4;
  const int rowbase = blockIdx.x * 128 + w * 32;
  const int arow0 = min(rowbase + lr, N - 1);
  const int arow1 = min(rowbase + 16 + lr, N - 1);

  f4_t acc[2][8];
  const f4_t zz = {0.f, 0.f, 0.f, 0.f};
  bf8_t a0[4], a1[4];

  STAGE_W(wbf + 16384, 256, 0);
#pragma unroll
  for (int s = 0; s < 4; ++s) {
    const int k0 = s * 32 + lg * 8;
    a0[s] = *(const bf8_t*)(xanb + (size_t)arow0 * FF + k0);
    a1[s] = *(const bf8_t*)(xanb + (size_t)arow1 * FF + k0);
  }
  __syncthreads();

#pragma unroll 1
  for (int gi = 0; gi < 2; ++gi) {
#pragma unroll
    for (int rg = 0; rg < 2; ++rg)
#pragma unroll
      for (int t = 0; t < 8; ++t) acc[rg][t] = zz;
#pragma unroll
    for (int s = 0; s < 4; ++s) {
#pragma unroll
      for (int t = 0; t < 8; ++t) {
        bf8_t b = *(const bf8_t*)&wlds[(s * 4 + lg) * 1024 + (t * 16 + lr) * 8];
        acc[0][t] = MFMA(a0[s], b, acc[0][t], 0, 0, 0);
        acc[1][t] = MFMA(a1[s], b, acc[1][t], 0, 0, 0);
      }
    }
    const float* bp = gi ? b1d : b1n;
    uint16_t* hp = gi ? h1d : h1n;
#pragma unroll
    for (int t = 0; t < 8; ++t) {
      const int col = t * 16 + lr;
      const float b = bp[col];
      float sum = 0.f, ss = 0.f;
#pragma unroll
      for (int rg = 0; rg < 2; ++rg)
#pragma unroll
        for (int r = 0; r < 4; ++r) {
          const int row = rowbase + rg * 16 + lg * 4 + r;
          const float h = acc[rg][t][r] + b;
          if (row < N) {
            hp[(size_t)row * FF + col] = f2bf(h);
            sum += h;
            ss += h * h;
          }
        }
      sum += __shfl_xor(sum, 16, 64);
      sum += __shfl_xor(sum, 32, 64);
      ss += __shfl_xor(ss, 16, 64);
      ss += __shfl_xor(ss, 32, 64);
      if (lane < 16) {
        sstat[w][gi * 2 + 0][col] = sum;
        sstat[w][gi * 2 + 1][col] = ss;
      }
    }
    if (gi == 0) {
      __syncthreads();
      STAGE_W(wbf + 3 * 16384, 256, 0);
#pragma unroll
      for (int s = 0; s < 4; ++s) {
        const int k0 = s * 32 + lg * 8;
        a0[s] = *(const bf8_t*)(xadb + (size_t)arow0 * FF + k0);
        a1[s] = *(const bf8_t*)(xadb + (size_t)arow1 * FF + k0);
      }
      __syncthreads();
    }
  }
  __syncthreads();
  for (int i = tid; i < 512; i += 256) {
    int a = i >> 7, c = i & 127;
    float v = sstat[0][a][c] + sstat[1][a][c] + sstat[2][a][c] + sstat[3][a][c];
    unsafeAtomicAdd(&gstats[i], v);
  }
}

// ---------------- BN finalize ----------------
__global__ void bnfin_k(const float* __restrict__ gstats,
                        const float* __restrict__ gamn, const float* __restrict__ betn,
                        const float* __restrict__ gamd, const float* __restrict__ betd,
                        float* __restrict__ bnp, int N) {
  int i = threadIdx.x;  // 128
  float invN = 1.f / (float)N;
  {
    float mu = gstats[i] * invN;
    float var = gstats[128 + i] * invN - mu * mu;
    float sc = gamn[i] * rsqrtf(var + 1e-5f);
    bnp[i] = sc;
    bnp[128 + i] = betn[i] - mu * sc;
  }
  {
    float mu = gstats[256 + i] * invN;
    float var = gstats[384 + i] * invN - mu * mu;
    float sc = gamd[i] * rsqrtf(var + 1e-5f);
    bnp[256 + i] = sc;
    bnp[384 + i] = betd[i] - mu * sc;
  }
}

// ---------------- stage 2: 6 staged weight phases, B from LDS ----------------
__global__ __launch_bounds__(256) void fuse2_k(
    const uint16_t* __restrict__ xb, const uint16_t* __restrict__ h1n,
    const uint16_t* __restrict__ h1d, const uint16_t* __restrict__ wbf,
    const float* __restrict__ bnp, const float* __restrict__ b_sl,
    const float* __restrict__ b2n, const float* __restrict__ b2d,
    const float* __restrict__ bgat, float* __restrict__ out, int N) {
  __shared__ __align__(16) uint16_t wlds[16384];      // staged weight (32KB)
  __shared__ __align__(16) uint16_t smt[4][16][136];  // per-wave tile, reused 3x
  const int tid = threadIdx.x;
  const int lane = tid & 63, w = tid >> 6;
  const int lr = lane & 15, lg = lane >> 4;
  const int rowbase = blockIdx.x * 64 + w * 16;
  const int arow = min(rowbase + lr, N - 1);
  const uint16_t* wg = wbf + 5 * 16384;

  f4_t sum[8];
  f4_t accG[8];
  f4_t wk[8];
  const f4_t zz = {0.f, 0.f, 0.f, 0.f};

#define GATE_PHASE()                                                             \
  do {                                                                          \
    _Pragma("unroll") for (int s = 0; s < 4; ++s) {                             \
      bf8_t a = *(const bf8_t*)&smt[w][lr][s * 32 + lg * 8];                    \
      _Pragma("unroll") for (int t = 0; t < 8; ++t) {                           \
        bf8_t b = *(const bf8_t*)&wlds[(s * 4 + lg) * 1024 + (t * 16 + lr) * 8]; \
        accG[t] = MFMA(a, b, accG[t], 0, 0, 0);                                 \
      }                                                                         \
    }                                                                           \
  } while (0)

#define BRANCH_PHASE(hv, bnb, bp, ADDSUM)                                        \
  do {                                                                          \
    _Pragma("unroll") for (int t = 0; t < 8; ++t) wk[t] = zz;                   \
    _Pragma("unroll") for (int s = 0; s < 4; ++s) {                             \
      const int k0 = s * 32 + lg * 8;                                           \
      f4_t sc0 = *(const f4_t*)((bnb) + k0);                                    \
      f4_t sc1 = *(const f4_t*)((bnb) + k0 + 4);                                \
      f4_t sh0 = *(const f4_t*)((bnb) + 128 + k0);                              \
      f4_t sh1 = *(const f4_t*)((bnb) + 128 + k0 + 4);                          \
      bf8_t a;                                                                  \
      _Pragma("unroll") for (int j = 0; j < 4; ++j) {                           \
        a[j] = (short)f2bf(fmaxf(bf2f((hv)[s][j]) * sc0[j] + sh0[j], 0.f));     \
        a[j + 4] =                                                              \
            (short)f2bf(fmaxf(bf2f((hv)[s][j + 4]) * sc1[j] + sh1[j], 0.f));    \
      }                                                                         \
      _Pragma("unroll") for (int t = 0; t < 8; ++t) {                           \
        bf8_t b = *(const bf8_t*)&wlds[(s * 4 + lg) * 1024 + (t * 16 + lr) * 8]; \
        wk[t] = MFMA(a, b, wk[t], 0, 0, 0);                                     \
      }                                                                         \
    }                                                                           \
    _Pragma("unroll") for (int t = 0; t < 8; ++t) {                             \
      const int col = t * 16 + lr;                                              \
      const float bb = (bp)[col];                                               \
      _Pragma("unroll") for (int r = 0; r < 4; ++r) {                           \
        const float v = wk[t][r] + bb;                                          \
        if (ADDSUM) sum[t][r] += v;                                             \
        smt[w][lg * 4 + r][col] = f2bf(v);                                      \
      }                                                                         \
    }                                                                           \
  } while (0)

  bf8_t xa[4];
#pragma unroll
  for (int s = 0; s < 4; ++s)
    xa[s] = *(const bf8_t*)(xb + (size_t)arow * FF + s * 32 + lg * 8);

  STAGE_W(wbf, 256, 0);  // wsl
  __syncthreads();

#pragma unroll
  for (int t = 0; t < 8; ++t) sum[t] = zz;
#pragma unroll
  for (int s = 0; s < 4; ++s) {
#pragma unroll
    for (int t = 0; t < 8; ++t) {
      bf8_t b = *(const bf8_t*)&wlds[(s * 4 + lg) * 1024 + (t * 16 + lr) * 8];
      sum[t] = MFMA(xa[s], b, sum[t], 0, 0, 0);
    }
  }
#pragma unroll
  for (int t = 0; t < 8; ++t) {
    const int col = t * 16 + lr;
    const float b = b_sl[col];
#pragma unroll
    for (int r = 0; r < 4; ++r) {
      sum[t][r] += b;
      smt[w][lg * 4 + r][col] = f2bf(sum[t][r]);
    }
  }
  us8_t hvn[4];
#pragma unroll
  for (int s = 0; s < 4; ++s)
    hvn[s] = *(const us8_t*)(h1n + (size_t)arow * FF + s * 32 + lg * 8);

  __syncthreads();
  STAGE_W(wg, 768, 0);  // wgat block 0
  __syncthreads();
#pragma unroll
  for (int t = 0; t < 8; ++t) accG[t] = zz;
  GATE_PHASE();

  __syncthreads();
  STAGE_W(wbf + 2 * 16384, 256, 0);  // w2n
  __syncthreads();
  BRANCH_PHASE(hvn, bnp, b2n, 1);
  us8_t hvd[4];
#pragma unroll
  for (int s = 0; s < 4; ++s)
    hvd[s] = *(const us8_t*)(h1d + (size_t)arow * FF + s * 32 + lg * 8);

  __syncthreads();
  STAGE_W(wg, 768, 256);  // wgat block 1
  __syncthreads();
  GATE_PHASE();

  __syncthreads();
  STAGE_W(wbf + 4 * 16384, 256, 0);  // w2d
  __syncthreads();
  BRANCH_PHASE(hvd, bnp + 256, b2d, 0);

  __syncthreads();
  STAGE_W(wg, 768, 512);  // wgat block 2
  __syncthreads();
  GATE_PHASE();

  float bg[8];
#pragma unroll
  for (int t = 0; t < 8; ++t) bg[t] = bgat[t * 16 + lr];
#pragma unroll
  for (int r = 0; r < 4; ++r) {
    float lv[8];
#pragma unroll
    for (int t = 0; t < 8; ++t) lv[t] = accG[t][r] + bg[t];
    float m = lv[0];
#pragma unroll
    for (int t = 1; t < 8; ++t) m = fmaxf(m, lv[t]);
#pragma unroll
    for (int d = 1; d < 16; d <<= 1) m = fmaxf(m, __shfl_xor(m, d, 16));
    float g[8];
    float run = 0.f;
#pragma unroll
    for (int t = 0; t < 8; ++t) {
      float p = __expf(lv[t] - m);
      float scn = p;
#pragma unroll
      for (int d = 1; d < 16; d <<= 1) {
        float o = __shfl_up(scn, (unsigned)d, 16);
        if (lr >= d) scn += o;
      }
      g[t] = run + scn;
      run += __shfl(scn, 15, 16);
    }
    const float inv = 1.f / run;
    const int row = rowbase + lg * 4 + r;
    if (row < N) {
      const int lrow = lg * 4 + r;
#pragma unroll
      for (int t = 0; t < 8; ++t) {
        const int col = t * 16 + lr;
        const float xdf = bf2f(smt[w][lrow][127 - col]);
        out[(size_t)row * FF + col] = sum[t][r] + xdf * (g[t] * inv);
      }
    }
  }
#undef GATE_PHASE
#undef BRANCH_PHASE
}

extern "C" void kernel_launch(void* const* d_in, const int* in_sizes, int n_in,
                              void* d_out, int out_size, void* d_ws, size_t ws_size,
                              hipStream_t stream) {
  const float* x = (const float*)d_in[0];
  const int* eidx = (const int*)d_in[1];
  const int* etype = (const int*)d_in[2];
  const float* w_sl = (const float*)d_in[3];
  const float* b_sl = (const float*)d_in[4];
  const float* w1n = (const float*)d_in[5];
  const float* b1n = (const float*)d_in[6];
  const float* gamn = (const float*)d_in[7];
  const float* betn = (const float*)d_in[8];
  const float* w2n = (const float*)d_in[9];
  const float* b2n = (const float*)d_in[10];
  const float* w1d = (const float*)d_in[11];
  const float* b1d = (const float*)d_in[12];
  const float* gamd = (const float*)d_in[13];
  const float* betd = (const float*)d_in[14];
  const float* w2d = (const float*)d_in[15];
  const float* b2d = (const float*)d_in[16];
  const float* wgat = (const float*)d_in[17];
  const float* bgat = (const float*)d_in[18];
  float* out = (float*)d_out;

  const int N = in_sizes[0] / FF;
  const int E = in_sizes[2];
  const int* src = eidx;
  const int* dst = eidx + E;
  const int nbins = 2 * N;
  const int nbuckets = (nbins + 511) >> 9;

  const size_t NF = (size_t)N * FF;
  float* gstats = (float*)d_ws;
  float* bnp = gstats + 512;
  uint16_t* wbf = (uint16_t*)(bnp + 512);  // 131072 u16
  uint16_t* xb = wbf + 131072;             // NF
  uint16_t* xanb = xb + NF;
  uint16_t* xadb = xanb + NF;
  uint16_t* h1n = xadb + NF;
  uint16_t* h1d = h1n + NF;
  int* hist = (int*)(h1d + NF);
  int* off = hist + nbins;        // nbins+1
  int* ccur = off + nbins + 1;    // nbuckets
  int* bsum = ccur + nbuckets;    // <=1024
  int* ssrc = bsum + 1024;        // E
  uint32_t* bk = (uint32_t*)(ssrc + E);  // E

  const int nb1 = (nbins + 255) / 256;

  hipMemsetAsync(hist, 0, (size_t)nbins * sizeof(int), stream);
  hipMemsetAsync(gstats, 0, 512 * sizeof(float), stream);
  cvt_w_k<<<512, 256, 0, stream>>>(w_sl, w1n, w2n, w1d, w2d, wgat, wbf);
  cvt_x_k<<<(int)((NF / 4 + 255) / 256), 256, 0, stream>>>(x, xb, (int)(NF / 4));

  hist_k<<<(E + 255) / 256, 256, 0, stream>>>(dst, etype, hist, E);
  scan1_k<<<nb1, 256, 0, stream>>>(hist, off, bsum, nbins);
  scan2_k<<<1, 1024, 0, stream>>>(bsum, nb1);
  scan3_k<<<(nbins + 256) / 256, 256, 0, stream>>>(off, ccur, bsum, nbins, E);
  bucketize_k<<<(E + 256 * BK_EPT - 1) / (256 * BK_EPT), 256, 0, stream>>>(
      src, dst, etype, ccur, bk, E, nbuckets);
  sctfine_k<<<nbuckets, 256, 0, stream>>>(off, bk, ssrc, nbins);
  agg_k<<<(nbins + 3) / 4, 256, 0, stream>>>(off, ssrc, xb, x, xanb, xadb, nbins);

  gemm1_k<<<(N + 127) / 128, 256, 0, stream>>>(xanb, xadb, wbf, b1n, b1d, h1n, h1d,
                                               gstats, N);
  bnfin_k<<<1, 128, 0, stream>>>(gstats, gamn, betn, gamd, betd, bnp, N);
  fuse2_k<<<(N + 63) / 64, 256, 0, stream>>>(xb, h1n, h1d, wbf, bnp, b_sl, b2n, b2d,
                                             bgat, out, N);
}

// Round 9
// 375.307 us; speedup vs baseline: 2.4244x; 1.0054x over previous
//
#include <hip/hip_runtime.h>
#include <stdint.h>

#define FF 128
#define MFMA __builtin_amdgcn_mfma_f32_16x16x32_bf16

typedef __attribute__((ext_vector_type(8))) short bf8_t;     // 8 x bf16 MFMA frag
typedef __attribute__((ext_vector_type(4))) float f4_t;      // MFMA acc
typedef __attribute__((ext_vector_type(8))) uint16_t us8_t;  // 8 x bf16 bits

__device__ __forceinline__ uint16_t f2bf(float f) {
  union { float f; uint32_t u; } v; v.f = f;
  return (uint16_t)((v.u + 0x7fffu + ((v.u >> 16) & 1u)) >> 16);  // RNE
}
__device__ __forceinline__ float bf2f(uint16_t h) {
  union { uint32_t u; float f; } v; v.u = ((uint32_t)h) << 16;
  return v.f;
}

// Stage one 128x128 bf16 weight matrix (32KB) into LDS, chunk-major, 8 waves:
// wlds byte layout: c*2048 + r*16, c = 16B-col-chunk (0..15), r = row (0..127).
#define STAGE_W8(Wp, rsb, cb)                                                  \
  do {                                                                         \
    uint4 tmp_[4];                                                             \
    _Pragma("unroll") for (int j_ = 0; j_ < 4; ++j_) {                         \
      int k_ = j_ * 8 + w;                                                     \
      int r_ = ((k_ & 1) << 6) + lane;                                         \
      int c_ = k_ >> 1;                                                        \
      tmp_[j_] = *(const uint4*)((const char*)(Wp) + (size_t)r_ * (rsb) +      \
                                 (cb) + c_ * 16);                              \
    }                                                                          \
    _Pragma("unroll") for (int j_ = 0; j_ < 4; ++j_) {                         \
      int k_ = j_ * 8 + w;                                                     \
      *(uint4*)((char*)wlds + k_ * 1024 + lane * 16) = tmp_[j_];               \
    }                                                                          \
  } while (0)

// ---------------- weights f32 -> bf16 ----------------
// layout: [wsl | w1n | w2n | w1d | w2d] each 128x128, then wgat 128x384
__global__ __launch_bounds__(256) void cvt_w_k(
    const float* __restrict__ wsl, const float* __restrict__ w1n,
    const float* __restrict__ w2n, const float* __restrict__ w1d,
    const float* __restrict__ w2d, const float* __restrict__ wgat,
    uint16_t* __restrict__ o) {
  int i = blockIdx.x * 256 + threadIdx.x;
  const int NW = 5 * 16384;
  if (i >= NW + 49152) return;
  float v;
  if (i < NW) {
    int wsel = i >> 14, j = i & 16383;
    const float* p = (wsel == 0) ? wsl : (wsel == 1) ? w1n : (wsel == 2) ? w2n
                     : (wsel == 3) ? w1d : w2d;
    v = p[j];
  } else {
    v = wgat[i - NW];
  }
  o[i] = f2bf(v);
}

// ---------------- x f32 -> bf16 ----------------
__global__ __launch_bounds__(256) void cvt_x_k(const float* __restrict__ x,
                                               uint16_t* __restrict__ xb, int n4) {
  int i = blockIdx.x * 256 + threadIdx.x;
  if (i >= n4) return;
  float4 v = ((const float4*)x)[i];
  uint2 o;
  o.x = ((uint32_t)f2bf(v.y) << 16) | f2bf(v.x);
  o.y = ((uint32_t)f2bf(v.w) << 16) | f2bf(v.z);
  ((uint2*)xb)[i] = o;
}

// ---------------- counting sort of edges by key = dst*2 + type ----------------
__global__ __launch_bounds__(256) void hist_k(const int* __restrict__ dst,
                                              const int* __restrict__ ety,
                                              int* __restrict__ hist, int E) {
  int i = blockIdx.x * 256 + threadIdx.x;
  if (i < E) atomicAdd(&hist[(dst[i] << 1) | ety[i]], 1);
}

__global__ __launch_bounds__(256) void scan1_k(const int* __restrict__ hist,
                                               int* __restrict__ off,
                                               int* __restrict__ bsum, int nbins) {
  int i = blockIdx.x * 256 + threadIdx.x;
  int v = (i < nbins) ? hist[i] : 0;
  int lane = threadIdx.x & 63, w = threadIdx.x >> 6;
  int s = v;
#pragma unroll
  for (int d = 1; d < 64; d <<= 1) {
    int o = __shfl_up(s, (unsigned)d, 64);
    if (lane >= d) s += o;
  }
  __shared__ int wsum[4];
  if (lane == 63) wsum[w] = s;
  __syncthreads();
  int add = 0;
  for (int k = 0; k < w; ++k) add += wsum[k];
  s += add;
  if (i < nbins) off[i] = s - v;  // exclusive
  if (threadIdx.x == 255) bsum[blockIdx.x] = s;
}

__global__ __launch_bounds__(1024) void scan2_k(int* __restrict__ bsum, int nb) {
  int t = threadIdx.x;
  int v = (t < nb) ? bsum[t] : 0;
  int lane = t & 63, w = t >> 6;
  int s = v;
#pragma unroll
  for (int d = 1; d < 64; d <<= 1) {
    int o = __shfl_up(s, (unsigned)d, 64);
    if (lane >= d) s += o;
  }
  __shared__ int ws[16];
  if (lane == 63) ws[w] = s;
  __syncthreads();
  int add = 0;
  for (int k = 0; k < w; ++k) add += ws[k];
  s += add;
  if (t < nb) bsum[t] = s - v;
}

// finalize fine offsets; also init coarse-bucket cursors ccur[b] = off[b*512]
__global__ __launch_bounds__(256) void scan3_k(int* __restrict__ off,
                                               int* __restrict__ ccur,
                                               const int* __restrict__ bsum,
                                               int nbins, int E) {
  int i = blockIdx.x * 256 + threadIdx.x;
  if (i < nbins) {
    int v = off[i] + bsum[blockIdx.x];
    off[i] = v;
    if ((i & 511) == 0) ccur[i >> 9] = v;
  }
  if (i == nbins) off[i] = E;
}

// ---------------- pass 1: LDS-aggregated coarse bucket scatter ----------------
#define BK_EPT 16
__global__ __launch_bounds__(256) void bucketize_k(const int* __restrict__ src,
                                                   const int* __restrict__ dst,
                                                   const int* __restrict__ ety,
                                                   int* __restrict__ ccur,
                                                   uint32_t* __restrict__ bk,
                                                   int E, int nbuckets) {
  __shared__ int lhist[512];
  __shared__ int lbase[512];
  const int tid = threadIdx.x;
  const int base = blockIdx.x * (256 * BK_EPT);
  for (int j = tid; j < nbuckets; j += 256) lhist[j] = 0;
  __syncthreads();

  uint32_t pk[BK_EPT];  // src | localbin<<17
  uint32_t rk[BK_EPT];  // bucket | rank<<9
#pragma unroll
  for (int j = 0; j < BK_EPT; ++j) {
    int i = base + j * 256 + tid;
    if (i < E) {
      int bin = (dst[i] << 1) | ety[i];
      int bucket = bin >> 9;
      int rank = atomicAdd(&lhist[bucket], 1);
      pk[j] = (uint32_t)src[i] | ((uint32_t)(bin & 511) << 17);
      rk[j] = (uint32_t)bucket | ((uint32_t)rank << 9);
    } else {
      rk[j] = 0xFFFFFFFFu;
    }
  }
  __syncthreads();
  for (int j = tid; j < nbuckets; j += 256) {
    int c = lhist[j];
    lbase[j] = c ? atomicAdd(&ccur[j], c) : 0;
  }
  __syncthreads();
#pragma unroll
  for (int j = 0; j < BK_EPT; ++j) {
    if (rk[j] != 0xFFFFFFFFu) {
      int bucket = (int)(rk[j] & 511u);
      int rank = (int)(rk[j] >> 9);
      bk[lbase[bucket] + rank] = pk[j];
    }
  }
}

// ---------------- pass 2: fine scatter within bucket (LDS cursors) ----------------
__global__ __launch_bounds__(256) void sctfine_k(const int* __restrict__ off,
                                                 const uint32_t* __restrict__ bk,
                                                 int* __restrict__ ssrc, int nbins) {
  __shared__ int lcur[512];
  const int b = blockIdx.x;
  const int binbase = b << 9;
  const int binend = min(binbase + 512, nbins);
  for (int j = threadIdx.x; j < binend - binbase; j += 256)
    lcur[j] = off[binbase + j];
  __syncthreads();
  const int estart = off[binbase], eend = off[binend];
  for (int i = estart + (int)threadIdx.x; i < eend; i += 256) {
    uint32_t pk = bk[i];
    int pos = atomicAdd(&lcur[pk >> 17], 1);
    ssrc[pos] = (int)(pk & 0x1FFFFu);
  }
}

// ---------------- segment-sum (bf16 gather) + own row: emits bf16 (x+agg) ----------------
__global__ __launch_bounds__(256) void agg_k(const int* __restrict__ off,
                                             const int* __restrict__ ssrc,
                                             const uint16_t* __restrict__ xb,
                                             const float* __restrict__ x,
                                             uint16_t* __restrict__ xanb,
                                             uint16_t* __restrict__ xadb, int nbins) {
  int wid = (blockIdx.x * 256 + threadIdx.x) >> 6;
  int lane = threadIdx.x & 63;
  if (wid >= nbins) return;
  int e = off[wid], end = off[wid + 1];
  float ax = 0.f, ay = 0.f, bx = 0.f, by = 0.f;
  for (; e + 7 < end; e += 8) {
    uint32_t v0 = ((const uint32_t*)(xb + (size_t)ssrc[e] * FF))[lane];
    uint32_t v1 = ((const uint32_t*)(xb + (size_t)ssrc[e + 1] * FF))[lane];
    uint32_t v2 = ((const uint32_t*)(xb + (size_t)ssrc[e + 2] * FF))[lane];
    uint32_t v3 = ((const uint32_t*)(xb + (size_t)ssrc[e + 3] * FF))[lane];
    uint32_t v4 = ((const uint32_t*)(xb + (size_t)ssrc[e + 4] * FF))[lane];
    uint32_t v5 = ((const uint32_t*)(xb + (size_t)ssrc[e + 5] * FF))[lane];
    uint32_t v6 = ((const uint32_t*)(xb + (size_t)ssrc[e + 6] * FF))[lane];
    uint32_t v7 = ((const uint32_t*)(xb + (size_t)ssrc[e + 7] * FF))[lane];
    ax += bf2f((uint16_t)(v0 & 0xffffu)) + bf2f((uint16_t)(v2 & 0xffffu)) +
          bf2f((uint16_t)(v4 & 0xffffu)) + bf2f((uint16_t)(v6 & 0xffffu));
    ay += bf2f((uint16_t)(v0 >> 16)) + bf2f((uint16_t)(v2 >> 16)) +
          bf2f((uint16_t)(v4 >> 16)) + bf2f((uint16_t)(v6 >> 16));
    bx += bf2f((uint16_t)(v1 & 0xffffu)) + bf2f((uint16_t)(v3 & 0xffffu)) +
          bf2f((uint16_t)(v5 & 0xffffu)) + bf2f((uint16_t)(v7 & 0xffffu));
    by += bf2f((uint16_t)(v1 >> 16)) + bf2f((uint16_t)(v3 >> 16)) +
          bf2f((uint16_t)(v5 >> 16)) + bf2f((uint16_t)(v7 >> 16));
  }
  for (; e + 1 < end; e += 2) {
    uint32_t v0 = ((const uint32_t*)(xb + (size_t)ssrc[e] * FF))[lane];
    uint32_t v1 = ((const uint32_t*)(xb + (size_t)ssrc[e + 1] * FF))[lane];
    ax += bf2f((uint16_t)(v0 & 0xffffu));
    ay += bf2f((uint16_t)(v0 >> 16));
    bx += bf2f((uint16_t)(v1 & 0xffffu));
    by += bf2f((uint16_t)(v1 >> 16));
  }
  if (e < end) {
    uint32_t v0 = ((const uint32_t*)(xb + (size_t)ssrc[e] * FF))[lane];
    ax += bf2f((uint16_t)(v0 & 0xffffu));
    ay += bf2f((uint16_t)(v0 >> 16));
  }
  ax += bx;
  ay += by;
  int n = wid >> 1;
  float2 xo = ((const float2*)(x + (size_t)n * FF))[lane];
  ax += xo.x;
  ay += xo.y;
  uint32_t o = ((uint32_t)f2bf(ay) << 16) | f2bf(ax);
  uint16_t* dstp = (wid & 1) ? xadb : xanb;
  ((uint32_t*)(dstp + (size_t)n * FF))[lane] = o;
}

// ---------------- stage 1: branch GEMM1s, 512 thr / 8 waves, 256 rows/block ----------------
__global__ __launch_bounds__(512) void gemm1_k(
    const uint16_t* __restrict__ xanb, const uint16_t* __restrict__ xadb,
    const uint16_t* __restrict__ wbf, const float* __restrict__ b1n,
    const float* __restrict__ b1d, uint16_t* __restrict__ h1n,
    uint16_t* __restrict__ h1d, float* __restrict__ gstats, int N) {
  __shared__ __align__(16) uint16_t wlds[16384];
  __shared__ float sstat[8][4][128];
  const int tid = threadIdx.x;
  const int lane = tid & 63, w = tid >> 6;
  const int lr = lane & 15, lg = lane >> 4;
  const int rowbase = blockIdx.x * 256 + w * 32;
  const int arow0 = min(rowbase + lr, N - 1);
  const int arow1 = min(rowbase + 16 + lr, N - 1);

  f4_t acc[2][8];
  const f4_t zz = {0.f, 0.f, 0.f, 0.f};
  bf8_t a0[4], a1[4];

  STAGE_W8(wbf + 16384, 256, 0);
#pragma unroll
  for (int s = 0; s < 4; ++s) {
    const int k0 = s * 32 + lg * 8;
    a0[s] = *(const bf8_t*)(xanb + (size_t)arow0 * FF + k0);
    a1[s] = *(const bf8_t*)(xanb + (size_t)arow1 * FF + k0);
  }
  __syncthreads();

#pragma unroll 1
  for (int gi = 0; gi < 2; ++gi) {
#pragma unroll
    for (int rg = 0; rg < 2; ++rg)
#pragma unroll
      for (int t = 0; t < 8; ++t) acc[rg][t] = zz;
#pragma unroll
    for (int s = 0; s < 4; ++s) {
#pragma unroll
      for (int t = 0; t < 8; ++t) {
        bf8_t b = *(const bf8_t*)&wlds[(s * 4 + lg) * 1024 + (t * 16 + lr) * 8];
        acc[0][t] = MFMA(a0[s], b, acc[0][t], 0, 0, 0);
        acc[1][t] = MFMA(a1[s], b, acc[1][t], 0, 0, 0);
      }
    }
    const float* bp = gi ? b1d : b1n;
    uint16_t* hp = gi ? h1d : h1n;
#pragma unroll
    for (int t = 0; t < 8; ++t) {
      const int col = t * 16 + lr;
      const float b = bp[col];
      float sum = 0.f, ss = 0.f;
#pragma unroll
      for (int rg = 0; rg < 2; ++rg)
#pragma unroll
        for (int r = 0; r < 4; ++r) {
          const int row = rowbase + rg * 16 + lg * 4 + r;
          const float h = acc[rg][t][r] + b;
          if (row < N) {
            hp[(size_t)row * FF + col] = f2bf(h);
            sum += h;
            ss += h * h;
          }
        }
      sum += __shfl_xor(sum, 16, 64);
      sum += __shfl_xor(sum, 32, 64);
      ss += __shfl_xor(ss, 16, 64);
      ss += __shfl_xor(ss, 32, 64);
      if (lane < 16) {
        sstat[w][gi * 2 + 0][col] = sum;
        sstat[w][gi * 2 + 1][col] = ss;
      }
    }
    if (gi == 0) {
      __syncthreads();
      STAGE_W8(wbf + 3 * 16384, 256, 0);
#pragma unroll
      for (int s = 0; s < 4; ++s) {
        const int k0 = s * 32 + lg * 8;
        a0[s] = *(const bf8_t*)(xadb + (size_t)arow0 * FF + k0);
        a1[s] = *(const bf8_t*)(xadb + (size_t)arow1 * FF + k0);
      }
      __syncthreads();
    }
  }
  __syncthreads();
  if (tid < 512) {
    int a = tid >> 7, c = tid & 127;
    float v = 0.f;
#pragma unroll
    for (int ww = 0; ww < 8; ++ww) v += sstat[ww][a][c];
    unsafeAtomicAdd(&gstats[tid], v);
  }
}

// ---------------- BN finalize ----------------
__global__ void bnfin_k(const float* __restrict__ gstats,
                        const float* __restrict__ gamn, const float* __restrict__ betn,
                        const float* __restrict__ gamd, const float* __restrict__ betd,
                        float* __restrict__ bnp, int N) {
  int i = threadIdx.x;  // 128
  float invN = 1.f / (float)N;
  {
    float mu = gstats[i] * invN;
    float var = gstats[128 + i] * invN - mu * mu;
    float sc = gamn[i] * rsqrtf(var + 1e-5f);
    bnp[i] = sc;
    bnp[128 + i] = betn[i] - mu * sc;
  }
  {
    float mu = gstats[256 + i] * invN;
    float var = gstats[384 + i] * invN - mu * mu;
    float sc = gamd[i] * rsqrtf(var + 1e-5f);
    bnp[256 + i] = sc;
    bnp[384 + i] = betd[i] - mu * sc;
  }
}

// ---------------- stage 2: 6 staged weight phases, 512 thr / 8 waves, 128 rows/block ----------------
__global__ __launch_bounds__(512) void fuse2_k(
    const uint16_t* __restrict__ xb, const uint16_t* __restrict__ h1n,
    const uint16_t* __restrict__ h1d, const uint16_t* __restrict__ wbf,
    const float* __restrict__ bnp, const float* __restrict__ b_sl,
    const float* __restrict__ b2n, const float* __restrict__ b2d,
    const float* __restrict__ bgat, float* __restrict__ out, int N) {
  __shared__ __align__(16) uint16_t wlds[16384];      // staged weight (32KB)
  __shared__ __align__(16) uint16_t smt[8][16][136];  // per-wave tile, reused 3x
  const int tid = threadIdx.x;
  const int lane = tid & 63, w = tid >> 6;
  const int lr = lane & 15, lg = lane >> 4;
  const int rowbase = blockIdx.x * 128 + w * 16;
  const int arow = min(rowbase + lr, N - 1);
  const uint16_t* wg = wbf + 5 * 16384;

  f4_t sum[8];
  f4_t accG[8];
  f4_t wk[8];
  const f4_t zz = {0.f, 0.f, 0.f, 0.f};

#define GATE_PHASE()                                                             \
  do {                                                                          \
    _Pragma("unroll") for (int s = 0; s < 4; ++s) {                             \
      bf8_t a = *(const bf8_t*)&smt[w][lr][s * 32 + lg * 8];                    \
      _Pragma("unroll") for (int t = 0; t < 8; ++t) {                           \
        bf8_t b = *(const bf8_t*)&wlds[(s * 4 + lg) * 1024 + (t * 16 + lr) * 8]; \
        accG[t] = MFMA(a, b, accG[t], 0, 0, 0);                                 \
      }                                                                         \
    }                                                                           \
  } while (0)

#define BRANCH_PHASE(hv, bnb, bp, ADDSUM)                                        \
  do {                                                                          \
    _Pragma("unroll") for (int t = 0; t < 8; ++t) wk[t] = zz;                   \
    _Pragma("unroll") for (int s = 0; s < 4; ++s) {                             \
      const int k0 = s * 32 + lg * 8;                                           \
      f4_t sc0 = *(const f4_t*)((bnb) + k0);                                    \
      f4_t sc1 = *(const f4_t*)((bnb) + k0 + 4);                                \
      f4_t sh0 = *(const f4_t*)((bnb) + 128 + k0);                              \
      f4_t sh1 = *(const f4_t*)((bnb) + 128 + k0 + 4);                          \
      bf8_t a;                                                                  \
      _Pragma("unroll") for (int j = 0; j < 4; ++j) {                           \
        a[j] = (short)f2bf(fmaxf(bf2f((hv)[s][j]) * sc0[j] + sh0[j], 0.f));     \
        a[j + 4] =                                                              \
            (short)f2bf(fmaxf(bf2f((hv)[s][j + 4]) * sc1[j] + sh1[j], 0.f));    \
      }                                                                         \
      _Pragma("unroll") for (int t = 0; t < 8; ++t) {                           \
        bf8_t b = *(const bf8_t*)&wlds[(s * 4 + lg) * 1024 + (t * 16 + lr) * 8]; \
        wk[t] = MFMA(a, b, wk[t], 0, 0, 0);                                     \
      }                                                                         \
    }                                                                           \
    _Pragma("unroll") for (int t = 0; t < 8; ++t) {                             \
      const int col = t * 16 + lr;                                              \
      const float bb = (bp)[col];                                               \
      _Pragma("unroll") for (int r = 0; r < 4; ++r) {                           \
        const float v = wk[t][r] + bb;                                          \
        if (ADDSUM) sum[t][r] += v;                                             \
        smt[w][lg * 4 + r][col] = f2bf(v);                                      \
      }                                                                         \
    }                                                                           \
  } while (0)

  bf8_t xa[4];
#pragma unroll
  for (int s = 0; s < 4; ++s)
    xa[s] = *(const bf8_t*)(xb + (size_t)arow * FF + s * 32 + lg * 8);

  STAGE_W8(wbf, 256, 0);  // wsl
  __syncthreads();

#pragma unroll
  for (int t = 0; t < 8; ++t) sum[t] = zz;
#pragma unroll
  for (int s = 0; s < 4; ++s) {
#pragma unroll
    for (int t = 0; t < 8; ++t) {
      bf8_t b = *(const bf8_t*)&wlds[(s * 4 + lg) * 1024 + (t * 16 + lr) * 8];
      sum[t] = MFMA(xa[s], b, sum[t], 0, 0, 0);
    }
  }
#pragma unroll
  for (int t = 0; t < 8; ++t) {
    const int col = t * 16 + lr;
    const float b = b_sl[col];
#pragma unroll
    for (int r = 0; r < 4; ++r) {
      sum[t][r] += b;
      smt[w][lg * 4 + r][col] = f2bf(sum[t][r]);
    }
  }
  us8_t hvn[4];
#pragma unroll
  for (int s = 0; s < 4; ++s)
    hvn[s] = *(const us8_t*)(h1n + (size_t)arow * FF + s * 32 + lg * 8);

  __syncthreads();
  STAGE_W8(wg, 768, 0);  // wgat block 0
  __syncthreads();
#pragma unroll
  for (int t = 0; t < 8; ++t) accG[t] = zz;
  GATE_PHASE();

  __syncthreads();
  STAGE_W8(wbf + 2 * 16384, 256, 0);  // w2n
  __syncthreads();
  BRANCH_PHASE(hvn, bnp, b2n, 1);
  us8_t hvd[4];
#pragma unroll
  for (int s = 0; s < 4; ++s)
    hvd[s] = *(const us8_t*)(h1d + (size_t)arow * FF + s * 32 + lg * 8);

  __syncthreads();
  STAGE_W8(wg, 768, 256);  // wgat block 1
  __syncthreads();
  GATE_PHASE();

  __syncthreads();
  STAGE_W8(wbf + 4 * 16384, 256, 0);  // w2d
  __syncthreads();
  BRANCH_PHASE(hvd, bnp + 256, b2d, 0);

  __syncthreads();
  STAGE_W8(wg, 768, 512);  // wgat block 2
  __syncthreads();
  GATE_PHASE();

  float bg[8];
#pragma unroll
  for (int t = 0; t < 8; ++t) bg[t] = bgat[t * 16 + lr];
#pragma unroll
  for (int r = 0; r < 4; ++r) {
    float lv[8];
#pragma unroll
    for (int t = 0; t < 8; ++t) lv[t] = accG[t][r] + bg[t];
    float m = lv[0];
#pragma unroll
    for (int t = 1; t < 8; ++t) m = fmaxf(m, lv[t]);
#pragma unroll
    for (int d = 1; d < 16; d <<= 1) m = fmaxf(m, __shfl_xor(m, d, 16));
    float g[8];
    float run = 0.f;
#pragma unroll
    for (int t = 0; t < 8; ++t) {
      float p = __expf(lv[t] - m);
      float scn = p;
#pragma unroll
      for (int d = 1; d < 16; d <<= 1) {
        float o = __shfl_up(scn, (unsigned)d, 16);
        if (lr >= d) scn += o;
      }
      g[t] = run + scn;
      run += __shfl(scn, 15, 16);
    }
    const float inv = 1.f / run;
    const int row = rowbase + lg * 4 + r;
    if (row < N) {
      const int lrow = lg * 4 + r;
#pragma unroll
      for (int t = 0; t < 8; ++t) {
        const int col = t * 16 + lr;
        const float xdf = bf2f(smt[w][lrow][127 - col]);
        out[(size_t)row * FF + col] = sum[t][r] + xdf * (g[t] * inv);
      }
    }
  }
#undef GATE_PHASE
#undef BRANCH_PHASE
}

extern "C" void kernel_launch(void* const* d_in, const int* in_sizes, int n_in,
                              void* d_out, int out_size, void* d_ws, size_t ws_size,
                              hipStream_t stream) {
  const float* x = (const float*)d_in[0];
  const int* eidx = (const int*)d_in[1];
  const int* etype = (const int*)d_in[2];
  const float* w_sl = (const float*)d_in[3];
  const float* b_sl = (const float*)d_in[4];
  const float* w1n = (const float*)d_in[5];
  const float* b1n = (const float*)d_in[6];
  const float* gamn = (const float*)d_in[7];
  const float* betn = (const float*)d_in[8];
  const float* w2n = (const float*)d_in[9];
  const float* b2n = (const float*)d_in[10];
  const float* w1d = (const float*)d_in[11];
  const float* b1d = (const float*)d_in[12];
  const float* gamd = (const float*)d_in[13];
  const float* betd = (const float*)d_in[14];
  const float* w2d = (const float*)d_in[15];
  const float* b2d = (const float*)d_in[16];
  const float* wgat = (const float*)d_in[17];
  const float* bgat = (const float*)d_in[18];
  float* out = (float*)d_out;

  const int N = in_sizes[0] / FF;
  const int E = in_sizes[2];
  const int* src = eidx;
  const int* dst = eidx + E;
  const int nbins = 2 * N;
  const int nbuckets = (nbins + 511) >> 9;

  const size_t NF = (size_t)N * FF;
  float* gstats = (float*)d_ws;
  float* bnp = gstats + 512;
  uint16_t* wbf = (uint16_t*)(bnp + 512);  // 131072 u16
  uint16_t* xb = wbf + 131072;             // NF
  uint16_t* xanb = xb + NF;
  uint16_t* xadb = xanb + NF;
  uint16_t* h1n = xadb + NF;
  uint16_t* h1d = h1n + NF;
  int* hist = (int*)(h1d + NF);
  int* off = hist + nbins;        // nbins+1
  int* ccur = off + nbins + 1;    // nbuckets
  int* bsum = ccur + nbuckets;    // <=1024
  int* ssrc = bsum + 1024;        // E
  uint32_t* bk = (uint32_t*)(ssrc + E);  // E

  const int nb1 = (nbins + 255) / 256;

  hipMemsetAsync(hist, 0, (size_t)nbins * sizeof(int), stream);
  hipMemsetAsync(gstats, 0, 512 * sizeof(float), stream);
  cvt_w_k<<<512, 256, 0, stream>>>(w_sl, w1n, w2n, w1d, w2d, wgat, wbf);
  cvt_x_k<<<(int)((NF / 4 + 255) / 256), 256, 0, stream>>>(x, xb, (int)(NF / 4));

  hist_k<<<(E + 255) / 256, 256, 0, stream>>>(dst, etype, hist, E);
  scan1_k<<<nb1, 256, 0, stream>>>(hist, off, bsum, nbins);
  scan2_k<<<1, 1024, 0, stream>>>(bsum, nb1);
  scan3_k<<<(nbins + 256) / 256, 256, 0, stream>>>(off, ccur, bsum, nbins, E);
  bucketize_k<<<(E + 256 * BK_EPT - 1) / (256 * BK_EPT), 256, 0, stream>>>(
      src, dst, etype, ccur, bk, E, nbuckets);
  sctfine_k<<<nbuckets, 256, 0, stream>>>(off, bk, ssrc, nbins);
  agg_k<<<(nbins + 3) / 4, 256, 0, stream>>>(off, ssrc, xb, x, xanb, xadb, nbins);

  gemm1_k<<<(N + 255) / 256, 512, 0, stream>>>(xanb, xadb, wbf, b1n, b1d, h1n, h1d,
                                               gstats, N);
  bnfin_k<<<1, 128, 0, stream>>>(gstats, gamn, betn, gamd, betd, bnp, N);
  fuse2_k<<<(N + 127) / 128, 512, 0, stream>>>(xb, h1n, h1d, wbf, bnp, b_sl, b2n,
                                               b2d, bgat, out, N);
}